// Round 3
// baseline (66.084 us; speedup 1.0000x reference)
//
#include <hip/hip_runtime.h>

#define BB 16
#define LL 4096
#define DD 768
#define CB 320
#define CHUNKS 128
#define ROWS (LL / CHUNKS)   // 32

// ---------------- Kernel 1: histogram + sinv + zero-out (one block per batch) --
// 1024 threads: each thread owns 4 (idx_x, idx_y) pairs held in registers
// across the histogram and sum passes (no vq re-read).
__global__ __launch_bounds__(1024) void k_hist(const int2* __restrict__ vq,
                                               int* __restrict__ cnt_ws,
                                               float* __restrict__ sinv,
                                               float* __restrict__ out) {
    __shared__ int cnt[2 * CB];
    __shared__ float wsum[16];
    const int b = blockIdx.x;
    const int t = threadIdx.x;

    if (t < 2 * CB) cnt[t] = 0;
    // zero this batch's output slice (atomic accumulation target in K2)
    if (t < DD) out[(size_t)b * DD + t] = 0.0f;
    __syncthreads();

    const int2* vb = vq + (size_t)b * LL;
    int2 v[4];
#pragma unroll
    for (int k = 0; k < 4; ++k) v[k] = vb[t + k * 1024];
#pragma unroll
    for (int k = 0; k < 4; ++k) {
        atomicAdd(&cnt[v[k].x], 1);
        atomicAdd(&cnt[CB + v[k].y], 1);
    }
    __syncthreads();

    // write histogram to workspace for K2
    if (t < 2 * CB) cnt_ws[(size_t)b * 2 * CB + t] = cnt[t];

    // sum of weights (second pass over register-held pairs)
    float lsum = 0.f;
#pragma unroll
    for (int k = 0; k < 4; ++k)
        lsum += 1.0f / (float)(cnt[v[k].x] + cnt[CB + v[k].y]);
    for (int o = 32; o > 0; o >>= 1) lsum += __shfl_down(lsum, o, 64);
    if ((t & 63) == 0) wsum[t >> 6] = lsum;
    __syncthreads();
    if (t == 0) {
        float s = 0.f;
#pragma unroll
        for (int i = 0; i < 16; ++i) s += wsum[i];
        sinv[b] = 1.0f / s;
    }
}

// ---------------- Kernel 2: fused weight-compute + weighted sum + atomic out ---
// grid = BB*CHUNKS blocks, 192 threads; thread t owns float4 at d = 4*t.
__global__ __launch_bounds__(192) void k_fused(const float* __restrict__ x,
                                               const int* __restrict__ cnt_ws,
                                               const float* __restrict__ sinv,
                                               const int2* __restrict__ vq,
                                               float* __restrict__ out) {
    __shared__ int cnt[2 * CB];
    __shared__ float wl[ROWS];
    const int blk = blockIdx.x;
    const int b = blk >> 7;           // / CHUNKS
    const int c = blk & (CHUNKS - 1); // % CHUNKS
    const int t = threadIdx.x;
    const int l0 = c * ROWS;

    const int* cb = cnt_ws + (size_t)b * 2 * CB;
    for (int i = t; i < 2 * CB; i += 192) cnt[i] = cb[i];
    __syncthreads();

    if (t < ROWS) {
        int2 v = vq[(size_t)b * LL + l0 + t];
        wl[t] = sinv[b] / (float)(cnt[v.x] + cnt[CB + v.y]);
    }
    __syncthreads();

    // x slice: input_feature[b, 1, l0.., :]
    const float4* xb = (const float4*)(x + ((size_t)(b * 2 + 1) * LL + l0) * DD);

    float ax = 0.f, ay = 0.f, az = 0.f, aw = 0.f;
#pragma unroll 8
    for (int r = 0; r < ROWS; ++r) {
        const float wi = wl[r];
        float4 v = xb[(size_t)r * (DD / 4) + t];
        ax = fmaf(wi, v.x, ax);
        ay = fmaf(wi, v.y, ay);
        az = fmaf(wi, v.z, az);
        aw = fmaf(wi, v.w, aw);
    }

    float* ob = out + (size_t)b * DD + 4 * t;
    atomicAdd(ob + 0, ax);
    atomicAdd(ob + 1, ay);
    atomicAdd(ob + 2, az);
    atomicAdd(ob + 3, aw);
}

extern "C" void kernel_launch(void* const* d_in, const int* in_sizes, int n_in,
                              void* d_out, int out_size, void* d_ws, size_t ws_size,
                              hipStream_t stream) {
    const float* x = (const float*)d_in[0];       // (16, 2, 4096, 768) fp32
    // d_in[1] = input_lengths: unused by the reference
    const int2* vq = (const int2*)d_in[2];        // (16, 4096, 2) int32

    // workspace layout
    int* cnt_ws = (int*)d_ws;                     // BB * 640 ints
    float* sinv = (float*)(cnt_ws + BB * 2 * CB); // BB floats

    float* out = (float*)d_out;                   // (16, 768) fp32

    k_hist<<<BB, 1024, 0, stream>>>(vq, cnt_ws, sinv, out);
    k_fused<<<BB * CHUNKS, 192, 0, stream>>>(x, cnt_ws, sinv, vq, out);
}

// Round 4
// 46.075 us; speedup vs baseline: 1.4343x; 1.4343x over previous
//
#include <hip/hip_runtime.h>

#define BB 16
#define LL 4096
#define DD 768
#define CB 320
#define SLICES 16
#define SLICE_F4 12          // float4 per slice = 48 floats
#define TPB 768
#define RPI 64               // rows in flight = TPB / SLICE_F4
#define ITERS (LL / RPI)     // 64

// One kernel does everything. Grid = BB*SLICES = 256 blocks, 768 threads.
// Block (b, slice): redundant per-batch histogram -> sinv -> pre-scaled
// weights in LDS -> register-accumulated weighted column sum -> direct out.
__global__ __launch_bounds__(TPB) void k_all(const float* __restrict__ x,
                                             const int2* __restrict__ vq,
                                             float* __restrict__ out) {
    __shared__ int   cnt[2 * CB];          // 2.5 KB
    __shared__ float wl[LL];               // 16 KB  (pre-scaled weights)
    __shared__ float4 red[RPI][SLICE_F4];  // 12 KB
    __shared__ float wsum[TPB / 64];
    __shared__ float s_sinv;

    const int blk = blockIdx.x;
    const int b = blk >> 4;                // / SLICES
    const int slice = blk & (SLICES - 1);  // % SLICES
    const int t = threadIdx.x;

    // ---- histogram (pairs held in registers, fully static indexing) ----
    if (t < 2 * CB) cnt[t] = 0;
    __syncthreads();

    const int2* vb = vq + (size_t)b * LL;
    // LL/TPB = 5.33: slots k=0..4 always valid; k=5 valid iff t < LL - 5*TPB
    int2 v0 = vb[t];
    int2 v1 = vb[t + TPB];
    int2 v2 = vb[t + 2 * TPB];
    int2 v3 = vb[t + 3 * TPB];
    int2 v4 = vb[t + 4 * TPB];
    const bool has5 = (t < LL - 5 * TPB);
    int2 v5 = has5 ? vb[t + 5 * TPB] : make_int2(0, 0);

    atomicAdd(&cnt[v0.x], 1); atomicAdd(&cnt[CB + v0.y], 1);
    atomicAdd(&cnt[v1.x], 1); atomicAdd(&cnt[CB + v1.y], 1);
    atomicAdd(&cnt[v2.x], 1); atomicAdd(&cnt[CB + v2.y], 1);
    atomicAdd(&cnt[v3.x], 1); atomicAdd(&cnt[CB + v3.y], 1);
    atomicAdd(&cnt[v4.x], 1); atomicAdd(&cnt[CB + v4.y], 1);
    if (has5) { atomicAdd(&cnt[v5.x], 1); atomicAdd(&cnt[CB + v5.y], 1); }
    __syncthreads();

    // ---- sum of 1/(cx+cy) -> sinv ----
    float lsum = 0.f;
    float w0 = 1.0f / (float)(cnt[v0.x] + cnt[CB + v0.y]);
    float w1 = 1.0f / (float)(cnt[v1.x] + cnt[CB + v1.y]);
    float w2 = 1.0f / (float)(cnt[v2.x] + cnt[CB + v2.y]);
    float w3 = 1.0f / (float)(cnt[v3.x] + cnt[CB + v3.y]);
    float w4 = 1.0f / (float)(cnt[v4.x] + cnt[CB + v4.y]);
    float w5 = has5 ? 1.0f / (float)(cnt[v5.x] + cnt[CB + v5.y]) : 0.f;
    lsum = w0 + w1 + w2 + w3 + w4 + w5;
    for (int o = 32; o > 0; o >>= 1) lsum += __shfl_down(lsum, o, 64);
    if ((t & 63) == 0) wsum[t >> 6] = lsum;
    __syncthreads();
    if (t == 0) {
        float s = 0.f;
#pragma unroll
        for (int i = 0; i < TPB / 64; ++i) s += wsum[i];
        s_sinv = 1.0f / s;
    }
    __syncthreads();

    // ---- pre-scaled weights into LDS ----
    const float si = s_sinv;
    wl[t] = si * w0;
    wl[t + TPB] = si * w1;
    wl[t + 2 * TPB] = si * w2;
    wl[t + 3 * TPB] = si * w3;
    wl[t + 4 * TPB] = si * w4;
    if (has5) wl[t + 5 * TPB] = si * w5;
    __syncthreads();

    // ---- stream this block's column slice ----
    const int r = t / SLICE_F4;            // 0..63
    const int d = t % SLICE_F4;            // 0..11
    const float4* xb = (const float4*)(x) +
                       ((size_t)(b * 2 + 1) * LL * DD) / 4 +
                       slice * SLICE_F4 + d;

    float ax = 0.f, ay = 0.f, az = 0.f, aw = 0.f;
#pragma unroll 4
    for (int i = 0; i < ITERS; ++i) {
        const int l = i * RPI + r;
        const float wi = wl[l];
        float4 vx = xb[(size_t)l * (DD / 4)];
        ax = fmaf(wi, vx.x, ax);
        ay = fmaf(wi, vx.y, ay);
        az = fmaf(wi, vx.z, az);
        aw = fmaf(wi, vx.w, aw);
    }
    float4 acc; acc.x = ax; acc.y = ay; acc.z = az; acc.w = aw;
    red[r][d] = acc;
    __syncthreads();

    // ---- reduce 64 row-partials per d-lane; 12 threads, unrolled ----
    if (t < SLICE_F4) {
        float4 s = red[0][t];
#pragma unroll 9
        for (int k = 1; k < RPI; ++k) {
            float4 v = red[k][t];
            s.x += v.x; s.y += v.y; s.z += v.z; s.w += v.w;
        }
        ((float4*)out)[(size_t)b * (DD / 4) + slice * SLICE_F4 + t] = s;
    }
}

extern "C" void kernel_launch(void* const* d_in, const int* in_sizes, int n_in,
                              void* d_out, int out_size, void* d_ws, size_t ws_size,
                              hipStream_t stream) {
    const float* x = (const float*)d_in[0];       // (16, 2, 4096, 768) fp32
    // d_in[1] = input_lengths: unused by the reference
    const int2* vq = (const int2*)d_in[2];        // (16, 4096, 2) int32
    float* out = (float*)d_out;                   // (16, 768) fp32

    k_all<<<BB * SLICES, TPB, 0, stream>>>(x, vq, out);
}

// Round 6
// 40.506 us; speedup vs baseline: 1.6315x; 1.1375x over previous
//
#include <hip/hip_runtime.h>

#define BB 16
#define LL 4096
#define DD 768
#define CB 320
#define TPB 192              // = DD/4: one float4 column per thread
#define ROWS 64              // rows per block (contiguous 192 KB chunk)
#define NCHUNK (LL / ROWS)   // 64 chunks per batch
#define NPAIR 21             // full strided pair-rounds; remainder 64 (t<64)

// ---------------- Kernel 1: fused hist + sinv + weighted partial sums ----------
// grid = BB*NCHUNK = 1024 blocks, 192 threads. Each block redundantly builds
// its batch's histogram (pairs packed in registers), computes sinv locally,
// derives the 64 pre-scaled row weights, then streams its CONTIGUOUS
// 64-row x-chunk accumulating one 768-float partial.
__global__ __launch_bounds__(TPB) void k_main(const float* __restrict__ x,
                                              const int2* __restrict__ vq,
                                              float* __restrict__ part) {
    __shared__ int   cnt[2 * CB];
    __shared__ float wl[ROWS];
    __shared__ float wsum[TPB / 64];
    __shared__ float s_sinv;

    const int blk = blockIdx.x;
    const int b = blk / NCHUNK;
    const int c = blk % NCHUNK;
    const int t = threadIdx.x;

    for (int i = t; i < 2 * CB; i += TPB) cnt[i] = 0;
    __syncthreads();

    // ---- load all pairs for batch b, packed 16+16 bits into registers ----
    const int2* vb = vq + (size_t)b * LL;
    unsigned int p[NPAIR + 1];
#pragma unroll
    for (int k = 0; k < NPAIR; ++k) {
        int2 v = vb[t + k * TPB];
        p[k] = (unsigned int)v.x | ((unsigned int)v.y << 16);
    }
    const bool has = (t < LL - NPAIR * TPB);   // t < 64
    {
        int2 v = has ? vb[t + NPAIR * TPB] : make_int2(0, 0);
        p[NPAIR] = (unsigned int)v.x | ((unsigned int)v.y << 16);
    }

    // ---- LDS histogram ----
#pragma unroll
    for (int k = 0; k < NPAIR; ++k) {
        atomicAdd(&cnt[p[k] & 0xFFFF], 1);
        atomicAdd(&cnt[CB + (p[k] >> 16)], 1);
    }
    if (has) {
        atomicAdd(&cnt[p[NPAIR] & 0xFFFF], 1);
        atomicAdd(&cnt[CB + (p[NPAIR] >> 16)], 1);
    }
    __syncthreads();

    // ---- sum of 1/(cx+cy) over all rows -> sinv (pairs still in regs) ----
    float lsum = 0.f;
#pragma unroll
    for (int k = 0; k < NPAIR; ++k)
        lsum += 1.0f / (float)(cnt[p[k] & 0xFFFF] + cnt[CB + (p[k] >> 16)]);
    if (has)
        lsum += 1.0f / (float)(cnt[p[NPAIR] & 0xFFFF] + cnt[CB + (p[NPAIR] >> 16)]);
    for (int o = 32; o > 0; o >>= 1) lsum += __shfl_down(lsum, o, 64);
    if ((t & 63) == 0) wsum[t >> 6] = lsum;
    __syncthreads();
    if (t == 0) s_sinv = 1.0f / (wsum[0] + wsum[1] + wsum[2]);
    __syncthreads();

    // ---- pre-scaled weights for this block's 64 rows ----
    if (t < ROWS) {
        int2 v = vb[c * ROWS + t];             // L2-hot re-read
        wl[t] = s_sinv / (float)(cnt[v.x] + cnt[CB + v.y]);
    }
    __syncthreads();

    // ---- contiguous stream: 64 rows x 3072 B; thread t owns float4 col t ----
    const float4* xb = (const float4*)(x + ((size_t)(b * 2 + 1) * LL +
                                            (size_t)c * ROWS) * DD);
    float ax = 0.f, ay = 0.f, az = 0.f, aw = 0.f;
#pragma unroll 8
    for (int r = 0; r < ROWS; ++r) {
        const float wi = wl[r];
        float4 v = xb[(size_t)r * (DD / 4) + t];
        ax = fmaf(wi, v.x, ax);
        ay = fmaf(wi, v.y, ay);
        az = fmaf(wi, v.z, az);
        aw = fmaf(wi, v.w, aw);
    }
    float4 o; o.x = ax; o.y = ay; o.z = az; o.w = aw;
    ((float4*)part)[(size_t)blk * (DD / 4) + t] = o;
}

// ---------------- Kernel 2: reduce partials -> out -----------------------------
// 48 blocks x 256 threads; block covers 64 (b,d4) lanes, 4 chunk-groups of 16.
__global__ __launch_bounds__(256) void k_reduce(const float* __restrict__ part,
                                                float* __restrict__ out) {
    __shared__ float4 red[3][64];
    const int t = threadIdx.x;
    const int lane = t & 63;
    const int cg = t >> 6;                        // 0..3
    const int i = blockIdx.x * 64 + lane;         // 0 .. BB*DD/4-1
    const int b = i / (DD / 4);
    const int d4 = i % (DD / 4);
    const float4* p = (const float4*)part;

    float ax = 0.f, ay = 0.f, az = 0.f, aw = 0.f;
    const int c0 = cg * (NCHUNK / 4);
#pragma unroll 8
    for (int c = c0; c < c0 + NCHUNK / 4; ++c) {
        float4 v = p[((size_t)(b * NCHUNK + c)) * (DD / 4) + d4];
        ax += v.x; ay += v.y; az += v.z; aw += v.w;
    }
    if (cg > 0) {
        float4 o; o.x = ax; o.y = ay; o.z = az; o.w = aw;
        red[cg - 1][lane] = o;
    }
    __syncthreads();
    if (cg == 0) {
        float4 r0 = red[0][lane], r1 = red[1][lane], r2 = red[2][lane];
        float4 o;
        o.x = ax + r0.x + r1.x + r2.x;
        o.y = ay + r0.y + r1.y + r2.y;
        o.z = az + r0.z + r1.z + r2.z;
        o.w = aw + r0.w + r1.w + r2.w;
        ((float4*)out)[i] = o;
    }
}

extern "C" void kernel_launch(void* const* d_in, const int* in_sizes, int n_in,
                              void* d_out, int out_size, void* d_ws, size_t ws_size,
                              hipStream_t stream) {
    const float* x = (const float*)d_in[0];       // (16, 2, 4096, 768) fp32
    // d_in[1] = input_lengths: unused by the reference
    const int2* vq = (const int2*)d_in[2];        // (16, 4096, 2) int32

    float* part = (float*)d_ws;                   // BB*NCHUNK*DD floats = 3.1 MB
    float* out = (float*)d_out;                   // (16, 768) fp32

    k_main<<<BB * NCHUNK, TPB, 0, stream>>>(x, vq, part);
    k_reduce<<<48, 256, 0, stream>>>(part, out);
}